// Round 3
// baseline (465.004 us; speedup 1.0000x reference)
//
#include <hip/hip_runtime.h>
#include <hip/hip_bf16.h>

typedef unsigned short u16;
typedef __attribute__((ext_vector_type(8))) short short8;   // 8 x bf16 bits (4 VGPRs)
typedef __attribute__((ext_vector_type(4))) float f32x4;

#define S_DIM 2048
#define D_DIM 2048
#define H_NUM 16
#define DH_NUM 64

__device__ __forceinline__ float bf2f(u16 v) {
    union { unsigned u; float f; } x; x.u = ((unsigned)v) << 16; return x.f;
}
__device__ __forceinline__ u16 f2bf(float f) {
    union { float f; unsigned u; } x; x.f = f;
    unsigned r = x.u + 0x7fff + ((x.u >> 16) & 1);   // RNE
    return (u16)(r >> 16);
}

// async global->LDS, 16B per lane; LDS dest = wave-uniform base + lane*16
__device__ __forceinline__ void gload16(const void* g, void* l) {
    __builtin_amdgcn_global_load_lds(
        (const __attribute__((address_space(1))) unsigned int*)g,
        (__attribute__((address_space(3))) unsigned int*)l, 16, 0, 0);
}

// ---------------------------------------------------------------------------
// Convert fp32 x -> bf16 (RNE). 4M elements, float4 per thread.
// ---------------------------------------------------------------------------
__global__ __launch_bounds__(256)
void cvt_bf16(const float* __restrict__ src, u16* __restrict__ dst)
{
    int i = (blockIdx.x * 256 + threadIdx.x) * 4;
    float4 v = *(const float4*)(src + i);
    ushort4 o;
    o.x = f2bf(v.x); o.y = f2bf(v.y); o.z = f2bf(v.z); o.w = f2bf(v.w);
    *(ushort4*)(dst + i) = o;
}

// ---------------------------------------------------------------------------
// Transpose 2048x2048, fp32 in -> bf16 out (64x64 LDS tiles)
// ---------------------------------------------------------------------------
__global__ __launch_bounds__(256)
void transpose_w(const float* __restrict__ src, u16* __restrict__ dst)
{
    __shared__ __attribute__((aligned(16))) u16 tile[64][65];
    const int tx = threadIdx.x & 63, ty = threadIdx.x >> 6;
    const int bx = blockIdx.x * 64, by = blockIdx.y * 64;
    for (int i = ty; i < 64; i += 4)
        tile[i][tx] = f2bf(src[(by + i) * D_DIM + bx + tx]);
    __syncthreads();
    for (int i = ty; i < 64; i += 4)
        dst[(bx + i) * D_DIM + by + tx] = tile[tx][i];
}

// ---------------------------------------------------------------------------
// GEMM: C = A[2048,2048] * Bt[2048,2048]^T (bf16 in, fp32 MFMA accum)
// 128x128 tile, BK=32, 4 waves (each 64x64), global_load_lds width=16,
// XOR chunk swizzle so ds_read_b128 fragment reads are ~conflict-free.
// mode: 0 = bf16 row-major, 1 = bf16 transposed (V^T), 2 = fp32 row-major.
// ---------------------------------------------------------------------------
__global__ __launch_bounds__(256, 2)
void gemm_bt(const u16* __restrict__ A, const u16* __restrict__ Bt,
             void* __restrict__ Cout, int mode)
{
    const int Kd = D_DIM, N = D_DIM, M = S_DIM;

    __shared__ __attribute__((aligned(16))) u16 As[128 * 32];
    __shared__ __attribute__((aligned(16))) u16 Bs[128 * 32];

    const int tid = threadIdx.x, lane = tid & 63, wave = tid >> 6;
    const int bm = blockIdx.x * 128, bn = blockIdx.y * 128;

    // staging: lane covers tile-row wave*32 + (lane>>2) (+16 for second half),
    // 16B chunk; global chunk index swizzled: g = (l&3) ^ ((l>>3)&3)
    const int lrow = lane >> 2;
    const int gchunk = (lane & 3) ^ ((lane >> 3) & 3);
    const long aoff0 = (long)(bm + wave * 32 + lrow) * Kd + gchunk * 8;
    const long aoff1 = aoff0 + 16L * Kd;
    const long boff0 = (long)(bn + wave * 32 + lrow) * Kd + gchunk * 8;
    const long boff1 = boff0 + 16L * Kd;
    u16* as0 = &As[wave * 1024];
    u16* as1 = &As[wave * 1024 + 512];
    u16* bs0 = &Bs[wave * 1024];
    u16* bs1 = &Bs[wave * 1024 + 512];

    const int wr = (wave >> 1) * 64, wc = (wave & 1) * 64;
    const int fr = lane & 15, fq = lane >> 4;

    f32x4 acc[4][4];
    for (int i = 0; i < 4; ++i)
        for (int j = 0; j < 4; ++j) { f32x4 z = {0.f, 0.f, 0.f, 0.f}; acc[i][j] = z; }

    for (int k0 = 0; k0 < Kd; k0 += 32) {
        gload16(A + aoff0 + k0, as0);
        gload16(A + aoff1 + k0, as1);
        gload16(Bt + boff0 + k0, bs0);
        gload16(Bt + boff1 + k0, bs1);
        __syncthreads();

        short8 af[4], bf[4];
#pragma unroll
        for (int i = 0; i < 4; ++i) {
            int m = wr + i * 16 + fr;
            int slot = fq ^ ((m >> 1) & 3);
            af[i] = *(const short8*)&As[m * 32 + slot * 8];
            int n = wc + i * 16 + fr;
            int slotb = fq ^ ((n >> 1) & 3);
            bf[i] = *(const short8*)&Bs[n * 32 + slotb * 8];
        }
#pragma unroll
        for (int i = 0; i < 4; ++i)
#pragma unroll
            for (int j = 0; j < 4; ++j)
                acc[i][j] = __builtin_amdgcn_mfma_f32_16x16x32_bf16(af[i], bf[j], acc[i][j], 0, 0, 0);
        __syncthreads();
    }

    // epilogue: D row = wr+i*16+fq*4+r, col = wc+j*16+fr
#pragma unroll
    for (int i = 0; i < 4; ++i) {
        int row = bm + wr + i * 16 + fq * 4;
#pragma unroll
        for (int j = 0; j < 4; ++j) {
            int col = bn + wc + j * 16 + fr;
#pragma unroll
            for (int r = 0; r < 4; ++r) {
                float val = acc[i][j][r];
                if (mode == 2)      ((float*)Cout)[(long)(row + r) * N + col] = val;
                else if (mode == 1) ((u16*)Cout)[(long)col * M + (row + r)] = f2bf(val);
                else                ((u16*)Cout)[(long)(row + r) * N + col] = f2bf(val);
            }
        }
    }
}

// ---------------------------------------------------------------------------
// Differential flash attention + fused GroupNorm epilogue.
// Block = (64 q-rows, 1 head); 4 waves, each 16 q-rows. Two online-softmax
// streams share K/V staging. P round-trips through per-wave LDS to convert
// MFMA C-layout -> A-layout. V comes pre-transposed (Vt[channel][token]).
// Q/K/Vt are bf16 (workspace); lambda & GN params are fp32 (input tensors).
// ---------------------------------------------------------------------------
__global__ __launch_bounds__(256, 2)
void diff_attn(const u16* __restrict__ Qm, const u16* __restrict__ Km,
               const u16* __restrict__ Vt,
               const float* __restrict__ lq1, const float* __restrict__ lk1,
               const float* __restrict__ lq2, const float* __restrict__ lk2,
               const float* __restrict__ gw, const float* __restrict__ gb,
               u16* __restrict__ Y)
{
    __shared__ __attribute__((aligned(16))) u16 K1s[64 * 72];
    __shared__ __attribute__((aligned(16))) u16 K2s[64 * 72];
    __shared__ __attribute__((aligned(16))) u16 Vts[128 * 72];
    __shared__ __attribute__((aligned(16))) u16 Ps[4][2][16 * 72];

    const int tid = threadIdx.x, lane = tid & 63, wave = tid >> 6;
    const int h = blockIdx.y;
    const int q0 = blockIdx.x * 64 + wave * 16;
    const int qr = lane & 15, qq = lane >> 4;

    // lambda scalar (tiny, redundant per block; cached)
    float d1 = 0.f, d2 = 0.f;
    for (int i = 0; i < DH_NUM; ++i) {
        d1 += lq1[i] * lk1[i];
        d2 += lq2[i] * lk2[i];
    }
    const float lam = __expf(d1) - __expf(d2) + 0.8f;

    // Q fragments (A-operand: m = lane&15, k = qq*8 + j), held for whole kernel
    short8 q1f[2], q2f[2];
    {
        const u16* qb = Qm + (long)(q0 + qr) * D_DIM + h * 128;
        q1f[0] = *(const short8*)(qb + qq * 8);
        q1f[1] = *(const short8*)(qb + 32 + qq * 8);
        q2f[0] = *(const short8*)(qb + 64 + qq * 8);
        q2f[1] = *(const short8*)(qb + 96 + qq * 8);
    }

    f32x4 acc1[8], acc2[8];
    for (int i = 0; i < 8; ++i) { f32x4 z = {0.f, 0.f, 0.f, 0.f}; acc1[i] = z; acc2[i] = z; }
    float m1[4], m2[4], l1[4], l2[4];
    for (int r = 0; r < 4; ++r) { m1[r] = -1e30f; m2[r] = -1e30f; l1[r] = 0.f; l2[r] = 0.f; }

    u16* psa = &Ps[wave][0][0];
    u16* psb = &Ps[wave][1][0];

    for (int kb = 0; kb < S_DIM / 64; ++kb) {
        __syncthreads();   // WAR: previous iteration's LDS reads complete
        // ---- stage K1, K2 (64x64 each) and Vt slice (128 ch x 64 tokens)
        {
            const long krow = (long)(kb * 64) * D_DIM + h * 128;
#pragma unroll
            for (int it = 0; it < 2; ++it) {
                int idx = tid + it * 256;          // 0..511
                int t = idx >> 3, c = idx & 7;
                *(short8*)&K1s[t * 72 + c * 8] =
                    *(const short8*)&Km[krow + (long)t * D_DIM + c * 8];
                *(short8*)&K2s[t * 72 + c * 8] =
                    *(const short8*)&Km[krow + (long)t * D_DIM + 64 + c * 8];
            }
#pragma unroll
            for (int it = 0; it < 4; ++it) {
                int idx = tid + it * 256;          // 0..1023
                int rr = idx >> 3, c = idx & 7;
                *(short8*)&Vts[rr * 72 + c * 8] =
                    *(const short8*)&Vt[(long)(h * 128 + rr) * S_DIM + kb * 64 + c * 8];
            }
        }
        __syncthreads();

        // ---- scores S1,S2: 16 q-rows x 64 keys (4 j-tiles x 2 k-steps)
        f32x4 sc1[4], sc2[4];
#pragma unroll
        for (int j = 0; j < 4; ++j) {
            f32x4 s1v = {0.f, 0.f, 0.f, 0.f}, s2v = {0.f, 0.f, 0.f, 0.f};
#pragma unroll
            for (int ks = 0; ks < 2; ++ks) {
                short8 k1 = *(const short8*)&K1s[(j * 16 + qr) * 72 + ks * 32 + qq * 8];
                short8 k2 = *(const short8*)&K2s[(j * 16 + qr) * 72 + ks * 32 + qq * 8];
                s1v = __builtin_amdgcn_mfma_f32_16x16x32_bf16(q1f[ks], k1, s1v, 0, 0, 0);
                s2v = __builtin_amdgcn_mfma_f32_16x16x32_bf16(q2f[ks], k2, s2v, 0, 0, 0);
            }
            sc1[j] = s1v * 0.125f;   // 1/sqrt(64)
            sc2[j] = s2v * 0.125f;
        }

        // ---- online softmax, both streams; rows live in quads (row=qq*4+r)
        float nm1[4], nm2[4];
#pragma unroll
        for (int r = 0; r < 4; ++r) {
            float v1 = fmaxf(fmaxf(sc1[0][r], sc1[1][r]), fmaxf(sc1[2][r], sc1[3][r]));
            float v2 = fmaxf(fmaxf(sc2[0][r], sc2[1][r]), fmaxf(sc2[2][r], sc2[3][r]));
            for (int off = 1; off < 16; off <<= 1) {
                v1 = fmaxf(v1, __shfl_xor(v1, off, 64));
                v2 = fmaxf(v2, __shfl_xor(v2, off, 64));
            }
            nm1[r] = fmaxf(m1[r], v1);
            nm2[r] = fmaxf(m2[r], v2);
        }
        float rs1[4] = {0.f, 0.f, 0.f, 0.f}, rs2[4] = {0.f, 0.f, 0.f, 0.f};
#pragma unroll
        for (int j = 0; j < 4; ++j)
#pragma unroll
            for (int r = 0; r < 4; ++r) {
                float p1 = __expf(sc1[j][r] - nm1[r]);
                float p2 = __expf(sc2[j][r] - nm2[r]);
                rs1[r] += p1; rs2[r] += p2;
                psa[(qq * 4 + r) * 72 + j * 16 + qr] = f2bf(p1);
                psb[(qq * 4 + r) * 72 + j * 16 + qr] = f2bf(p2);
            }
#pragma unroll
        for (int r = 0; r < 4; ++r) {
            for (int off = 1; off < 16; off <<= 1) {
                rs1[r] += __shfl_xor(rs1[r], off, 64);
                rs2[r] += __shfl_xor(rs2[r], off, 64);
            }
            float a1 = __expf(m1[r] - nm1[r]);
            float a2 = __expf(m2[r] - nm2[r]);
            m1[r] = nm1[r]; m2[r] = nm2[r];
            l1[r] = l1[r] * a1 + rs1[r];
            l2[r] = l2[r] * a2 + rs2[r];
#pragma unroll
            for (int nt = 0; nt < 8; ++nt) { acc1[nt][r] *= a1; acc2[nt][r] *= a2; }
        }
        __syncthreads();   // Ps ordered before any wave proceeds

        // ---- PV: O += P * V   (A-frag from Ps, B-frag from Vts)
        short8 pa1[2], pa2[2];
#pragma unroll
        for (int ks = 0; ks < 2; ++ks) {
            pa1[ks] = *(const short8*)&psa[qr * 72 + ks * 32 + qq * 8];
            pa2[ks] = *(const short8*)&psb[qr * 72 + ks * 32 + qq * 8];
        }
#pragma unroll
        for (int nt = 0; nt < 8; ++nt) {
#pragma unroll
            for (int ks = 0; ks < 2; ++ks) {
                short8 vf = *(const short8*)&Vts[(nt * 16 + qr) * 72 + ks * 32 + qq * 8];
                acc1[nt] = __builtin_amdgcn_mfma_f32_16x16x32_bf16(pa1[ks], vf, acc1[nt], 0, 0, 0);
                acc2[nt] = __builtin_amdgcn_mfma_f32_16x16x32_bf16(pa2[ks], vf, acc2[nt], 0, 0, 0);
            }
        }
    }

    // ---- epilogue: combine streams, GroupNorm over 128 ch, scale, store bf16
    float o[8][4], mean[4], varv[4];
#pragma unroll
    for (int r = 0; r < 4; ++r) {
        float i1 = 1.f / l1[r], i2 = lam / l2[r];
        float s = 0.f;
#pragma unroll
        for (int nt = 0; nt < 8; ++nt) {
            o[nt][r] = acc1[nt][r] * i1 - acc2[nt][r] * i2;
            s += o[nt][r];
        }
        for (int off = 1; off < 16; off <<= 1) s += __shfl_xor(s, off, 64);
        mean[r] = s * (1.f / 128.f);
        float v = 0.f;
#pragma unroll
        for (int nt = 0; nt < 8; ++nt) { float d = o[nt][r] - mean[r]; v += d * d; }
        for (int off = 1; off < 16; off <<= 1) v += __shfl_xor(v, off, 64);
        varv[r] = v * (1.f / 128.f);
    }
#pragma unroll
    for (int nt = 0; nt < 8; ++nt) {
        float gwv = gw[h * 128 + nt * 16 + qr];
        float gbv = gb[h * 128 + nt * 16 + qr];
#pragma unroll
        for (int r = 0; r < 4; ++r) {
            float inv = rsqrtf(varv[r] + 1e-5f);
            float val = ((o[nt][r] - mean[r]) * inv * gwv + gbv) * 0.2f;  // *(1-lambda_init)
            Y[(long)(q0 + qq * 4 + r) * D_DIM + h * 128 + nt * 16 + qr] = f2bf(val);
        }
    }
}

// ---------------------------------------------------------------------------
// Workspace: 5 x 8 MiB bf16 segments = 40 MiB.
//   S0: x(bf16)        -> reused as Yb after QKV GEMMs
//   S1: W^T (bf16, Wq/Wk/Wv/Wo sequentially)
//   S2: Q   S3: K   S4: V^T
// ---------------------------------------------------------------------------
extern "C" void kernel_launch(void* const* d_in, const int* in_sizes, int n_in,
                              void* d_out, int out_size, void* d_ws, size_t ws_size,
                              hipStream_t stream)
{
    const float* x   = (const float*)d_in[0];
    const float* Wq  = (const float*)d_in[1];
    const float* Wk  = (const float*)d_in[2];
    const float* Wv  = (const float*)d_in[3];
    const float* Wo  = (const float*)d_in[4];
    const float* lq1 = (const float*)d_in[5];
    const float* lk1 = (const float*)d_in[6];
    const float* lq2 = (const float*)d_in[7];
    const float* lk2 = (const float*)d_in[8];
    const float* gw  = (const float*)d_in[9];
    const float* gb  = (const float*)d_in[10];

    char* ws = (char*)d_ws;
    const size_t SEG = (size_t)D_DIM * D_DIM * sizeof(u16);   // 8 MiB
    u16* XB = (u16*)(ws + 0 * SEG);   // x bf16, later Yb
    u16* WT = (u16*)(ws + 1 * SEG);
    u16* Qb = (u16*)(ws + 2 * SEG);
    u16* Kb = (u16*)(ws + 3 * SEG);
    u16* Vt = (u16*)(ws + 4 * SEG);

    const dim3 tgrid(32, 32), ggrid(16, 16), agrid(32, 16);

    // x -> bf16
    cvt_bf16<<<4096, 256, 0, stream>>>(x, XB);
    // Q = x Wq
    transpose_w<<<tgrid, 256, 0, stream>>>(Wq, WT);
    gemm_bt<<<ggrid, 256, 0, stream>>>(XB, WT, Qb, 0);
    // K = x Wk
    transpose_w<<<tgrid, 256, 0, stream>>>(Wk, WT);
    gemm_bt<<<ggrid, 256, 0, stream>>>(XB, WT, Kb, 0);
    // V^T = (x Wv)^T
    transpose_w<<<tgrid, 256, 0, stream>>>(Wv, WT);
    gemm_bt<<<ggrid, 256, 0, stream>>>(XB, WT, Vt, 1);
    // attention + GroupNorm -> Yb (XB segment; x is dead)
    diff_attn<<<agrid, 256, 0, stream>>>(Qb, Kb, Vt, lq1, lk1, lq2, lk2,
                                         gw, gb, XB);
    // out = Yb Wo  (fp32 output)
    transpose_w<<<tgrid, 256, 0, stream>>>(Wo, WT);
    gemm_bt<<<ggrid, 256, 0, stream>>>(XB, WT, d_out, 2);
}